// Round 4
// baseline (593.964 us; speedup 1.0000x reference)
//
#include <hip/hip_runtime.h>
#include <math.h>

#define B_   32
#define C_   64
#define T_   12
#define NV   883
#define TTW  10          // T-2 output time steps
#define K3   2649        // 3*NV
#define KSEG 28          // k-tiles per 883-segment (28*32=896, zero-padded)

typedef __attribute__((ext_vector_type(8))) short bf16x8;   // 8 bf16 = 4 VGPRs (MFMA A/B frag)
typedef __attribute__((ext_vector_type(4))) float f32x4;    // MFMA C/D frag
typedef __attribute__((ext_vector_type(4))) unsigned int u32x4;

// ---- workspace layout (all 16B aligned) ----
// Apk: [b*12+s][kt<28][af<4][lane<64] x 16B  = 384*28*4*1024 = 44,040,192
// Bpk: [bx2<14][seg<3][kt<28][bfi<4][lane]   = 14*3*28*4*1024 = 4,816,896
// Wpk: [(gi*8+df)*2+kc][lane]                = 48*1024 = 49,152
#define WS_A_OFF   0ull
#define WS_A_BYTES 44040192ull
#define WS_B_OFF   (WS_A_OFF + WS_A_BYTES)
#define WS_B_BYTES 4816896ull
#define WS_W_OFF   (WS_B_OFF + WS_B_BYTES)
#define WS_W_BYTES 49152ull
#define WS_NEED    (WS_W_OFF + WS_W_BYTES)   // 48,906,240

__device__ __forceinline__ unsigned short f2bf(float f) {
    union { float f; unsigned int u; } v; v.f = f;
    unsigned int r = v.u + 0x7fffu + ((v.u >> 16) & 1u);   // RNE
    return (unsigned short)(r >> 16);
}

// ---------------- prep kernels ----------------

// A-pack, fully parallel, no LDS: wave handles (bs, af), 7 kt per block-row.
// grid (384, 4) x 256 threads. Lane reads 8 consecutive k of channel c=af*16+lo.
__global__ __launch_bounds__(256) void prep_a(const float* __restrict__ x,
                                              const float* __restrict__ temb,
                                              const float* __restrict__ semb,
                                              u32x4* __restrict__ Apk) {
    const int tid  = threadIdx.x;
    const int w    = tid >> 6;
    const int lane = tid & 63;
    const int q    = lane >> 4;
    const int lo   = lane & 15;
    const int bs   = blockIdx.x;          // 0..383 = b*12 + s
    const int b    = bs / 12, s = bs - b * 12;
    const int af   = w;
    const int c    = af * 16 + lo;

    const float te = temb[c * T_ + s];
    const float* xr = x + ((size_t)(b * C_ + c) * T_ + s) * NV;
    const float* sr = semb + (size_t)c * NV;

#pragma unroll
    for (int ki = 0; ki < 7; ++ki) {
        const int kt = blockIdx.y * 7 + ki;
        const int k0 = kt * 32 + q * 8;
        unsigned short u[8];
#pragma unroll
        for (int i = 0; i < 8; ++i) {
            const int k = k0 + i;
            float v = (k < NV) ? (xr[k] + te + sr[k]) : 0.f;
            u[i] = f2bf(v);
        }
        u32x4 pk;
        pk[0] = u[0] | ((unsigned)u[1] << 16);
        pk[1] = u[2] | ((unsigned)u[3] << 16);
        pk[2] = u[4] | ((unsigned)u[5] << 16);
        pk[3] = u[6] | ((unsigned)u[7] << 16);
        Apk[(size_t)((bs * KSEG + kt) * 4 + af) * 64 + lane] = pk;
    }
}

// B-pack: adj middle rows -> bf16 B-fragments split per time-segment, zero-padded K.
__global__ __launch_bounds__(256) void prep_b(const float* __restrict__ adj,
                                              u32x4* __restrict__ Bpk) {
    const int chunk = blockIdx.x * 4 + (threadIdx.x >> 6);   // 0..4703
    const int l = threadIdx.x & 63;
    const int bfi = chunk & 3;
    int tmp = chunk >> 2;
    const int kt = tmp % KSEG;  tmp /= KSEG;
    const int seg = tmp % 3;
    const int bx2 = tmp / 3;                                  // 0..13
    const int m16 = bx2 * 4 + bfi;                            // 0..55
    const int row = NV + m16 * 16 + (l & 15);                 // <= 1778 < 2649
    const float* src = adj + (size_t)row * K3 + seg * NV;
    const int k0 = kt * 32 + (l >> 4) * 8;
    unsigned short u[8];
#pragma unroll
    for (int i = 0; i < 8; ++i) {
        const int kk = k0 + i;
        u[i] = (kk < NV) ? f2bf(src[kk]) : (unsigned short)0;
    }
    u32x4 pk;
    pk[0] = u[0] | ((unsigned)u[1] << 16);
    pk[1] = u[2] | ((unsigned)u[3] << 16);
    pk[2] = u[4] | ((unsigned)u[5] << 16);
    pk[3] = u[6] | ((unsigned)u[7] << 16);
    Bpk[(size_t)chunk * 64 + l] = pk;
}

// W-pack: [gi][c][2C] -> bf16 B-fragments. chunk = (gi*8+df)*2 + kc.
__global__ __launch_bounds__(256) void prep_w(const float* __restrict__ W,
                                              u32x4* __restrict__ Wpk) {
    const int chunk = blockIdx.x * 4 + (threadIdx.x >> 6);   // 0..47
    const int l = threadIdx.x & 63;
    const int c24 = chunk >> 1;
    const int kc  = chunk & 1;
    const int gi  = c24 >> 3;
    const int df  = c24 & 7;
    const int d   = 16 * df + (l & 15);
    const int c0  = kc * 32 + (l >> 4) * 8;
    const float* src = W + (size_t)gi * C_ * 128 + d;
    unsigned short u[8];
#pragma unroll
    for (int i = 0; i < 8; ++i) u[i] = f2bf(src[(size_t)(c0 + i) * 128]);
    u32x4 pk;
    pk[0] = u[0] | ((unsigned)u[1] << 16);
    pk[1] = u[2] | ((unsigned)u[3] << 16);
    pk[2] = u[4] | ((unsigned)u[5] << 16);
    pk[3] = u[6] | ((unsigned)u[7] << 16);
    Wpk[(size_t)chunk * 64 + l] = pk;
}

// ---------------- main kernel: t-chained register GEMM + fused GLU epilogue ----------------
// block = 128 threads = 2 waves (mh). Each wave: 64 m x 2 adjacent t-windows x 64 c.
// Stage-1 iterates 4 segments; shared segments feed both windows' accumulators.
__global__ __launch_bounds__(128, 2) void stsgcl_main(
    const bf16x8* __restrict__ Apk,
    const bf16x8* __restrict__ Bpk,
    const bf16x8* __restrict__ Wpk,
    const float* __restrict__ bias,
    float* __restrict__ out)
{
    __shared__ short Gs[2 * 2 * 64 * 72];   // [wave][bt][m=64][c=72 padded] = 36,864 B

    const int tid  = threadIdx.x;
    const int lane = tid & 63;
    const int w    = tid >> 6;              // 0..1 = m-half
    const int q    = lane >> 4;
    const int lo   = lane & 15;

    // XCD-aware swizzle: each XCD owns 20 consecutive bt-pairs x all 7 m-strips.
    const int lin  = blockIdx.y * 7 + blockIdx.x;   // 0..1119
    const int xcd  = lin & 7;
    const int idx  = lin >> 3;                      // 0..139
    const int slot = xcd * 140 + idx;
    const int bx   = slot % 7;
    const int yy   = slot / 7;                      // 0..159
    const int bb   = yy / 5;
    const int tq   = yy - bb * 5;
    const int t0   = tq * 2;                        // windows t0, t0+1
    const int bx2  = bx * 2 + w;                    // 0..13

    f32x4 acc[2][4][4];                             // [bt][af][bf]
#pragma unroll
    for (int bt = 0; bt < 2; ++bt)
#pragma unroll
        for (int i = 0; i < 4; ++i)
#pragma unroll
            for (int j = 0; j < 4; ++j)
#pragma unroll
                for (int r = 0; r < 4; ++r) acc[bt][i][j][r] = 0.f;

    // ---- stage 1: 4 segments, A shared between the two windows ----
#pragma unroll
    for (int s4 = 0; s4 < 4; ++s4) {
        const int s = t0 + s4;
        const bf16x8* ap  = Apk + (size_t)((bb * T_ + s) * KSEG) * 256 + lane;
        const int j0 = (s4 < 3) ? s4 : 0;           // window0 seg (valid s4<3)
        const int j1 = (s4 > 0) ? s4 - 1 : 0;       // window1 seg (valid s4>0)
        const bf16x8* bp0 = Bpk + (size_t)((bx2 * 3 + j0) * KSEG) * 256 + lane;
        const bf16x8* bp1 = Bpk + (size_t)((bx2 * 3 + j1) * KSEG) * 256 + lane;
#pragma unroll 2
        for (int kt = 0; kt < KSEG; ++kt) {
            bf16x8 av[4];
#pragma unroll
            for (int i = 0; i < 4; ++i) av[i] = ap[i * 64];
            ap += 256;
            if (s4 < 3) {
                bf16x8 bv[4];
#pragma unroll
                for (int i = 0; i < 4; ++i) bv[i] = bp0[i * 64];
                bp0 += 256;
#pragma unroll
                for (int i = 0; i < 4; ++i)
#pragma unroll
                    for (int j = 0; j < 4; ++j)
                        acc[0][i][j] = __builtin_amdgcn_mfma_f32_16x16x32_bf16(av[i], bv[j], acc[0][i][j], 0, 0, 0);
            }
            if (s4 > 0) {
                bf16x8 bv[4];
#pragma unroll
                for (int i = 0; i < 4; ++i) bv[i] = bp1[i * 64];
                bp1 += 256;
#pragma unroll
                for (int i = 0; i < 4; ++i)
#pragma unroll
                    for (int j = 0; j < 4; ++j)
                        acc[1][i][j] = __builtin_amdgcn_mfma_f32_16x16x32_bf16(av[i], bv[j], acc[1][i][j], 0, 0, 0);
            }
        }
    }

    // ---- transpose both g tiles (D-layout: c rows x m cols) -> Gs[m][c] bf16 ----
#pragma unroll
    for (int bt = 0; bt < 2; ++bt) {
        short* gw = &Gs[(w * 2 + bt) * (64 * 72)];
#pragma unroll
        for (int af = 0; af < 4; ++af)
#pragma unroll
            for (int bf = 0; bf < 4; ++bf) {
                uint2 pk;
                pk.x = (unsigned)f2bf(acc[bt][af][bf][0]) | ((unsigned)f2bf(acc[bt][af][bf][1]) << 16);
                pk.y = (unsigned)f2bf(acc[bt][af][bf][2]) | ((unsigned)f2bf(acc[bt][af][bf][3]) << 16);
                *(uint2*)&gw[(16 * bf + lo) * 72 + 16 * af + 4 * q] = pk;   // c=16af+4q+r, m=16bf+lo
            }
    }
    // same-wave RAW through LDS only (each wave reads its own region): no barrier needed.

    // ---- stage 2: gi-outer with W hoisted in registers; om[mg][df][r] kept across gi ----
#pragma unroll 1
    for (int bt = 0; bt < 2; ++bt) {
        const short* gw = &Gs[(w * 2 + bt) * (64 * 72)];
        float om[4][4][4];
#pragma unroll
        for (int mg = 0; mg < 4; ++mg)
#pragma unroll
            for (int df = 0; df < 4; ++df)
#pragma unroll
                for (int r = 0; r < 4; ++r) om[mg][df][r] = -3.4e38f;

#pragma unroll 1
        for (int gi = 0; gi < 3; ++gi) {
            bf16x8 wf[16];
#pragma unroll
            for (int df = 0; df < 8; ++df) {
                wf[df * 2 + 0] = Wpk[(size_t)((gi * 8 + df) * 2 + 0) * 64 + lane];
                wf[df * 2 + 1] = Wpk[(size_t)((gi * 8 + df) * 2 + 1) * 64 + lane];
            }
#pragma unroll 1
            for (int mg = 0; mg < 4; ++mg) {
                const short* arow = &gw[(16 * mg + lo) * 72];
                const bf16x8 a2k0 = *(const bf16x8*)&arow[q * 8];
                const bf16x8 a2k1 = *(const bf16x8*)&arow[32 + q * 8];
                f32x4 z[8];
#pragma unroll
                for (int i = 0; i < 8; ++i)
#pragma unroll
                    for (int r = 0; r < 4; ++r) z[i][r] = 0.f;
#pragma unroll
                for (int df = 0; df < 8; ++df) {
                    z[df] = __builtin_amdgcn_mfma_f32_16x16x32_bf16(a2k0, wf[df * 2 + 0], z[df], 0, 0, 0);
                    z[df] = __builtin_amdgcn_mfma_f32_16x16x32_bf16(a2k1, wf[df * 2 + 1], z[df], 0, 0, 0);
                }
#pragma unroll
                for (int df = 0; df < 4; ++df) {
                    const float b1 = bias[gi * 128 + 16 * df + lo];
                    const float b2 = bias[gi * 128 + 64 + 16 * df + lo];
#pragma unroll
                    for (int r = 0; r < 4; ++r) {
                        const float z1 = z[df][r] + b1;
                        const float z2 = z[df + 4][r] + b2;
                        const float sg = 1.0f / (1.0f + __expf(-z2));
                        om[mg][df][r] = fmaxf(om[mg][df][r], z1 * sg);
                    }
                }
            }
        }

        const int t = t0 + bt;
#pragma unroll
        for (int mg = 0; mg < 4; ++mg) {
            const int m16g = bx2 * 4 + mg;          // 0..55
            const int mvb  = m16g * 16 + 4 * q;
#pragma unroll
            for (int df = 0; df < 4; ++df) {
                const int cout = 16 * df + lo;
                float* orow = out + ((size_t)(bb * C_ + cout) * TTW + t) * NV + mvb;
#pragma unroll
                for (int r = 0; r < 4; ++r) {
                    if (mvb + r < NV) orow[r] = om[mg][df][r];
                }
            }
        }
    }
}

// ---------------- fallback: round-1 verified fp32 kernel (tiny ws) ----------------
__global__ __launch_bounds__(256) void stsgcl_fused(
    const float* __restrict__ x, const float* __restrict__ temb,
    const float* __restrict__ semb, const float* __restrict__ adj,
    const float* __restrict__ Wg, const float* __restrict__ bias,
    float* __restrict__ out)
{
    __shared__ union {
        struct { float As[32][64]; float Bs[32][64]; } s1;
        float Ws[64][128];
    } sm;
    __shared__ float Gsf[64][64];

    const int tid = threadIdx.x;
    const int bt = blockIdx.y;
    const int bb = bt / TTW;
    const int t  = bt % TTW;
    const int m0 = blockIdx.x * 64;
    const int tr = tid >> 4, tc = tid & 15;
    const int lrow = tid >> 2;
    const int kq = (tid & 3) * 8;

    const float* xrow = x + ((size_t)(bb * C_ + lrow) * T_ + t) * NV;
    const float* brow = adj + (size_t)(NV + m0 + lrow) * K3;
    const float* srow = semb + (size_t)lrow * NV;
    const float te0 = temb[lrow * T_ + t], te1 = temb[lrow * T_ + t + 1], te2 = temb[lrow * T_ + t + 2];

    float acc[4][4];
#pragma unroll
    for (int i = 0; i < 4; ++i)
#pragma unroll
        for (int j = 0; j < 4; ++j) acc[i][j] = 0.f;

    for (int kt = 0; kt < (K3 + 31) / 32; ++kt) {
        const int kg0 = kt * 32 + kq;
        {
            int tt, n;
            if (kg0 >= 2 * NV) { tt = 2; n = kg0 - 2 * NV; }
            else if (kg0 >= NV) { tt = 1; n = kg0 - NV; }
            else { tt = 0; n = kg0; }
#pragma unroll
            for (int i = 0; i < 8; ++i) {
                float v = 0.f;
                if (kg0 + i < K3) {
                    const float tev = (tt == 0) ? te0 : ((tt == 1) ? te1 : te2);
                    v = xrow[tt * NV + n] + tev + srow[n];
                }
                sm.s1.As[kq + i][lrow] = v;
                if (++n == NV) { n = 0; ++tt; }
            }
        }
#pragma unroll
        for (int i = 0; i < 8; ++i) sm.s1.Bs[kq + i][lrow] = brow[kg0 + i];
        __syncthreads();
#pragma unroll
        for (int kk = 0; kk < 32; ++kk) {
            const float4 a = *(const float4*)&sm.s1.As[kk][tr * 4];
            const float4 bv = *(const float4*)&sm.s1.Bs[kk][tc * 4];
            const float av[4] = {a.x, a.y, a.z, a.w};
            const float bw[4] = {bv.x, bv.y, bv.z, bv.w};
#pragma unroll
            for (int i = 0; i < 4; ++i)
#pragma unroll
                for (int j = 0; j < 4; ++j) acc[i][j] += av[i] * bw[j];
        }
        __syncthreads();
    }
#pragma unroll
    for (int i = 0; i < 4; ++i)
#pragma unroll
        for (int j = 0; j < 4; ++j) Gsf[tr * 4 + i][tc * 4 + j] = acc[i][j];

    const int pg = tid & 15, cg = tid >> 4;
    float omax[4][4];
#pragma unroll
    for (int i = 0; i < 4; ++i)
#pragma unroll
        for (int j = 0; j < 4; ++j) omax[i][j] = -3.4e38f;

    for (int gi = 0; gi < 3; ++gi) {
        __syncthreads();
        {
            const float4* wsrc = (const float4*)(Wg + (size_t)gi * C_ * 128);
            float4* wdst = (float4*)&sm.Ws[0][0];
#pragma unroll
            for (int i = 0; i < 8; ++i) wdst[tid + i * 256] = wsrc[tid + i * 256];
        }
        __syncthreads();
        float z1[4][4], z2[4][4];
#pragma unroll
        for (int j = 0; j < 4; ++j) {
            const float b1 = bias[gi * 128 + cg * 4 + j];
            const float b2 = bias[gi * 128 + 64 + cg * 4 + j];
#pragma unroll
            for (int i = 0; i < 4; ++i) { z1[i][j] = b1; z2[i][j] = b2; }
        }
#pragma unroll 8
        for (int cc = 0; cc < 64; ++cc) {
            const float4 gv = *(const float4*)&Gsf[cc][pg * 4];
            const float4 w1 = *(const float4*)&sm.Ws[cc][cg * 4];
            const float4 w2 = *(const float4*)&sm.Ws[cc][64 + cg * 4];
            const float gva[4] = {gv.x, gv.y, gv.z, gv.w};
            const float w1a[4] = {w1.x, w1.y, w1.z, w1.w};
            const float w2a[4] = {w2.x, w2.y, w2.z, w2.w};
#pragma unroll
            for (int i = 0; i < 4; ++i)
#pragma unroll
                for (int j = 0; j < 4; ++j) { z1[i][j] += gva[i] * w1a[j]; z2[i][j] += gva[i] * w2a[j]; }
        }
#pragma unroll
        for (int i = 0; i < 4; ++i)
#pragma unroll
            for (int j = 0; j < 4; ++j) {
                const float s = 1.0f / (1.0f + __expf(-z2[i][j]));
                omax[i][j] = fmaxf(omax[i][j], z1[i][j] * s);
            }
    }
    const int mmb = m0 + pg * 4;
#pragma unroll
    for (int j = 0; j < 4; ++j) {
        const int co = cg * 4 + j;
        float* orow = out + ((size_t)(bb * C_ + co) * TTW + t) * NV;
#pragma unroll
        for (int i = 0; i < 4; ++i) {
            const int mm = mmb + i;
            if (mm < NV) orow[mm] = omax[i][j];
        }
    }
}

extern "C" void kernel_launch(void* const* d_in, const int* in_sizes, int n_in,
                              void* d_out, int out_size, void* d_ws, size_t ws_size,
                              hipStream_t stream) {
    (void)in_sizes; (void)n_in; (void)out_size;
    const float* x    = (const float*)d_in[0];
    const float* temb = (const float*)d_in[1];
    const float* semb = (const float*)d_in[2];
    const float* adj  = (const float*)d_in[3];
    const float* Wg   = (const float*)d_in[4];
    const float* bias = (const float*)d_in[5];
    float* out = (float*)d_out;

    if (ws_size >= (size_t)WS_NEED) {
        u32x4* Apk = (u32x4*)((char*)d_ws + WS_A_OFF);
        u32x4* Bpk = (u32x4*)((char*)d_ws + WS_B_OFF);
        u32x4* Wpk = (u32x4*)((char*)d_ws + WS_W_OFF);

        prep_a<<<dim3(384, 4), 256, 0, stream>>>(x, temb, semb, Apk);
        prep_b<<<dim3(1176), 256, 0, stream>>>(adj, Bpk);
        prep_w<<<dim3(12), 256, 0, stream>>>(Wg, Wpk);

        dim3 grid(7, 160);
        stsgcl_main<<<grid, 128, 0, stream>>>((const bf16x8*)Apk, (const bf16x8*)Bpk,
                                              (const bf16x8*)Wpk, bias, out);
    } else {
        dim3 grid(14, B_ * TTW);
        stsgcl_fused<<<grid, 256, 0, stream>>>(x, temb, semb, adj, Wg, bias, out);
    }
}